// Round 2
// baseline (280.727 us; speedup 1.0000x reference)
//
#include <hip/hip_runtime.h>
#include <math.h>

constexpr int BDIM  = 256;
constexpr int Bsz   = 16, Asz = 3, Hsz = 80, Wsz = 80;
constexpr int Csz   = 84;                 // 4 + 80
constexpr int HWsz  = Hsz * Wsz;          // 6400
constexpr int BAsz  = Bsz * Asz;          // 48
constexpr int NTGT  = 64;
constexpr int NCOMBO = BAsz * NTGT;       // 3072
constexpr int NF4   = Bsz * Asz * HWsz * (Csz / 4);  // 6,451,200 float4s
constexpr int BLOCKS = 2100;
constexpr int ITERS  = 12;
constexpr int STRIDE = BLOCKS * BDIM;     // 537600 == 21 * 25600 (≡0 mod 21)
static_assert(BLOCKS * BDIM * ITERS == NF4, "exact cover");
static_assert(STRIDE % 21 == 0, "rem invariant");

__device__ __forceinline__ float softplus_f(float x) {
    // matches jax.nn.softplus = logaddexp(x, 0): stable for both signs
    return log1pf(expf(-fabsf(x))) + fmaxf(x, 0.f);
}

__global__ __launch_bounds__(BDIM)
void yolo_main(const float* __restrict__ pred,
               const float* __restrict__ targets,
               float* __restrict__ acc) {
    int tid = blockIdx.x * BDIM + threadIdx.x;

    float sp_all = 0.f, sp_tgt = 0.f, loc = 0.f, cls = 0.f, obj = 0.f;

    // --- no-obj path: coalesced full stream, float4 per lane ---
    // Each float4 lies entirely within one cell (84 = 21*4). A float4 at
    // index i carries channel 4 in .x iff i % 21 == 1. Since STRIDE % 21
    // == 0, i % 21 == tid % 21 for every iteration of this thread.
    const float4* __restrict__ p4v = (const float4*)pred;
    bool carrier = (tid % 21) == 1;
    float4 v[ITERS];
    #pragma unroll
    for (int k = 0; k < ITERS; ++k) {
        v[k] = p4v[tid + k * STRIDE];
    }
    if (carrier) {
        #pragma unroll
        for (int k = 0; k < ITERS; ++k) sp_all += softplus_f(v[k].x);
    }

    // --- target path: first 3072 threads, one (b,a,target) combo each ---
    if (tid < NCOMBO) {
        int t  = tid & (NTGT - 1);
        int ba = tid >> 6;                    // NTGT == 64
        float cid_f = targets[t * 5 + 0];
        float tx    = targets[t * 5 + 1];
        float ty    = targets[t * 5 + 2];
        float tw    = targets[t * 5 + 3];
        float th    = targets[t * 5 + 4];
        int gx = min(max((int)floorf(tx * (float)Wsz), 0), Wsz - 1);
        int gy = min(max((int)floorf(ty * (float)Hsz), 0), Hsz - 1);
        int cell = gy * Wsz + gx;
        const float* p = pred + ((size_t)ba * HWsz + cell) * Csz;
        const float4* pv = (const float4*)p;   // cell base is 16B-aligned (336B stride)

        float4 c0 = pv[0];                     // channels 0..3
        float d0 = c0.x - tx, d1 = c0.y - ty, d2 = c0.z - tw, d3 = c0.w - th;
        loc = d0 * d0 + d1 * d1 + d2 * d2 + d3 * d3;

        // cls: channels 4..83 = float4s 1..20
        float csum = 0.f;
        float p4 = 0.f;
        #pragma unroll
        for (int j = 1; j < 21; ++j) {
            float4 w = pv[j];
            if (j == 1) p4 = w.x;              // channel 4
            csum += softplus_f(w.x) + softplus_f(w.y) +
                    softplus_f(w.z) + softplus_f(w.w);
        }
        int cid = (int)cid_f;
        csum -= p[4 + cid];
        cls = csum;

        obj    = softplus_f(-p4);
        sp_tgt = softplus_f(p4);   // subtracted from no-obj sum
    }

    // --- block reduction of 5 accumulators ---
    float vals[5] = {sp_all, sp_tgt, loc, cls, obj};
    #pragma unroll
    for (int k = 0; k < 5; ++k) {
        float s = vals[k];
        #pragma unroll
        for (int o = 32; o > 0; o >>= 1) s += __shfl_down(s, o, 64);
        vals[k] = s;
    }
    __shared__ float sm[4][5];
    int lane = threadIdx.x & 63, wid = threadIdx.x >> 6;
    if (lane == 0) {
        #pragma unroll
        for (int k = 0; k < 5; ++k) sm[wid][k] = vals[k];
    }
    __syncthreads();
    if (threadIdx.x == 0) {
        #pragma unroll
        for (int k = 0; k < 5; ++k) {
            float s = sm[0][k] + sm[1][k] + sm[2][k] + sm[3][k];
            atomicAdd(&acc[k], s);
        }
    }
}

__global__ void yolo_final(const float* __restrict__ acc, float* __restrict__ out) {
    float sp_all = acc[0], sp_tgt = acc[1], loc = acc[2], cls = acc[3], obj = acc[4];
    float loc_loss = loc / (float)(NCOMBO * 4);                 // 12288
    float cls_loss = cls / (float)(NCOMBO * 80);                // 245760
    float obj_loss = obj / (float)NCOMBO;                       // 3072
    float noobj    = (sp_all - sp_tgt) / (float)(BAsz * (HWsz - NTGT)); // 304128
    out[0] = loc_loss + cls_loss + obj_loss + 0.5f * noobj;
}

extern "C" void kernel_launch(void* const* d_in, const int* in_sizes, int n_in,
                              void* d_out, int out_size, void* d_ws, size_t ws_size,
                              hipStream_t stream) {
    const float* pred    = (const float*)d_in[0];
    const float* targets = (const float*)d_in[1];
    float* acc = (float*)d_ws;           // 5 floats of scratch
    float* out = (float*)d_out;

    hipMemsetAsync(acc, 0, 5 * sizeof(float), stream);
    yolo_main<<<BLOCKS, BDIM, 0, stream>>>(pred, targets, acc);
    yolo_final<<<1, 1, 0, stream>>>(acc, out);
}

// Round 3
// 159.454 us; speedup vs baseline: 1.7606x; 1.7606x over previous
//
#include <hip/hip_runtime.h>
#include <math.h>

constexpr int BDIM  = 256;
constexpr int Bsz   = 16, Asz = 3, Hsz = 80, Wsz = 80;
constexpr int Csz   = 84;                 // 4 + 80
constexpr int HWsz  = Hsz * Wsz;          // 6400
constexpr int BAsz  = Bsz * Asz;          // 48
constexpr int TOTAL = BAsz * HWsz;        // 307200
constexpr int NTGT  = 64;
constexpr int NCOMBO = BAsz * NTGT;       // 3072
constexpr int NBLK  = TOTAL / BDIM;       // 1200

__device__ __forceinline__ float softplus_f(float x) {
    // matches jax.nn.softplus = logaddexp(x, 0): stable for both signs
    return log1pf(expf(-fabsf(x))) + fmaxf(x, 0.f);
}

__global__ __launch_bounds__(BDIM)
void yolo_main(const float* __restrict__ pred,
               const float* __restrict__ targets,
               float* __restrict__ partial) {
    int tid = blockIdx.x * BDIM + threadIdx.x;

    float sp_all = 0.f, sp_tgt = 0.f, loc = 0.f, cls = 0.f, obj = 0.f;

    // --- no-obj path: one anchor-cell per thread, channel 4 only ---
    // Minimal HBM line traffic: 307200 distinct 64B lines = 19.7 MB.
    {
        float p4 = pred[(size_t)tid * Csz + 4];
        sp_all = softplus_f(p4);
    }

    // --- target path: first 3072 threads, one (b,a,target) combo each ---
    if (tid < NCOMBO) {
        int t  = tid & (NTGT - 1);
        int ba = tid >> 6;                    // NTGT == 64
        float cid_f = targets[t * 5 + 0];
        float tx    = targets[t * 5 + 1];
        float ty    = targets[t * 5 + 2];
        float tw    = targets[t * 5 + 3];
        float th    = targets[t * 5 + 4];
        int gx = min(max((int)floorf(tx * (float)Wsz), 0), Wsz - 1);
        int gy = min(max((int)floorf(ty * (float)Hsz), 0), Hsz - 1);
        int cell = gy * Wsz + gx;
        const float* p = pred + ((size_t)ba * HWsz + cell) * Csz;
        const float4* pv = (const float4*)p;   // cell base is 16B-aligned (336B stride)

        float4 c0 = pv[0];                     // channels 0..3
        float d0 = c0.x - tx, d1 = c0.y - ty, d2 = c0.z - tw, d3 = c0.w - th;
        loc = d0 * d0 + d1 * d1 + d2 * d2 + d3 * d3;

        // cls: channels 4..83 = float4s 1..20
        float csum = 0.f;
        float p4 = 0.f;
        #pragma unroll
        for (int j = 1; j < 21; ++j) {
            float4 w = pv[j];
            if (j == 1) p4 = w.x;              // channel 4
            csum += softplus_f(w.x) + softplus_f(w.y) +
                    softplus_f(w.z) + softplus_f(w.w);
        }
        int cid = (int)cid_f;
        csum -= p[4 + cid];
        cls = csum;

        obj    = softplus_f(-p4);
        sp_tgt = softplus_f(p4);   // subtracted from no-obj sum
    }

    // --- block reduction of 5 accumulators ---
    float vals[5] = {sp_all, sp_tgt, loc, cls, obj};
    #pragma unroll
    for (int k = 0; k < 5; ++k) {
        float s = vals[k];
        #pragma unroll
        for (int o = 32; o > 0; o >>= 1) s += __shfl_down(s, o, 64);
        vals[k] = s;
    }
    __shared__ float sm[4][5];
    int lane = threadIdx.x & 63, wid = threadIdx.x >> 6;
    if (lane == 0) {
        #pragma unroll
        for (int k = 0; k < 5; ++k) sm[wid][k] = vals[k];
    }
    __syncthreads();
    // per-block partial sums: NO global atomics (cross-XCD same-line atomics
    // serialized the previous rounds at ~15-19 ns/op)
    if (threadIdx.x == 0) {
        #pragma unroll
        for (int k = 0; k < 5; ++k) {
            partial[blockIdx.x * 5 + k] = sm[0][k] + sm[1][k] + sm[2][k] + sm[3][k];
        }
    }
}

__global__ __launch_bounds__(BDIM)
void yolo_final(const float* __restrict__ partial, float* __restrict__ out) {
    float s[5] = {0.f, 0.f, 0.f, 0.f, 0.f};
    for (int i = threadIdx.x; i < NBLK; i += BDIM) {
        #pragma unroll
        for (int k = 0; k < 5; ++k) s[k] += partial[i * 5 + k];
    }
    #pragma unroll
    for (int k = 0; k < 5; ++k) {
        float v = s[k];
        #pragma unroll
        for (int o = 32; o > 0; o >>= 1) v += __shfl_down(v, o, 64);
        s[k] = v;
    }
    __shared__ float sm[4][5];
    int lane = threadIdx.x & 63, wid = threadIdx.x >> 6;
    if (lane == 0) {
        #pragma unroll
        for (int k = 0; k < 5; ++k) sm[wid][k] = s[k];
    }
    __syncthreads();
    if (threadIdx.x == 0) {
        float sp_all = sm[0][0] + sm[1][0] + sm[2][0] + sm[3][0];
        float sp_tgt = sm[0][1] + sm[1][1] + sm[2][1] + sm[3][1];
        float loc    = sm[0][2] + sm[1][2] + sm[2][2] + sm[3][2];
        float cls    = sm[0][3] + sm[1][3] + sm[2][3] + sm[3][3];
        float obj    = sm[0][4] + sm[1][4] + sm[2][4] + sm[3][4];
        float loc_loss = loc / (float)(NCOMBO * 4);                 // 12288
        float cls_loss = cls / (float)(NCOMBO * 80);                // 245760
        float obj_loss = obj / (float)NCOMBO;                       // 3072
        float noobj    = (sp_all - sp_tgt) / (float)(BAsz * (HWsz - NTGT)); // 304128
        out[0] = loc_loss + cls_loss + obj_loss + 0.5f * noobj;
    }
}

extern "C" void kernel_launch(void* const* d_in, const int* in_sizes, int n_in,
                              void* d_out, int out_size, void* d_ws, size_t ws_size,
                              hipStream_t stream) {
    const float* pred    = (const float*)d_in[0];
    const float* targets = (const float*)d_in[1];
    float* partial = (float*)d_ws;       // 1200*5 floats of scratch, fully overwritten
    float* out = (float*)d_out;

    yolo_main<<<NBLK, BDIM, 0, stream>>>(pred, targets, partial);
    yolo_final<<<1, BDIM, 0, stream>>>(partial, out);
}

// Round 4
// 155.596 us; speedup vs baseline: 1.8042x; 1.0248x over previous
//
#include <hip/hip_runtime.h>
#include <math.h>

constexpr int BDIM  = 256;
constexpr int Bsz   = 16, Asz = 3, Hsz = 80, Wsz = 80;
constexpr int Csz   = 84;                 // 4 + 80
constexpr int HWsz  = Hsz * Wsz;          // 6400
constexpr int BAsz  = Bsz * Asz;          // 48
constexpr int TOTAL = BAsz * HWsz;        // 307200
constexpr int NTGT  = 64;
constexpr int NCOMBO = BAsz * NTGT;       // 3072
constexpr int GBLK  = TOTAL / BDIM;       // 1200 gather blocks
constexpr int TBLK  = BAsz;               // 48 target blocks (one per (b,a))
constexpr int NBLK  = GBLK + TBLK;        // 1248

// fast softplus: logaddexp(x,0) via hw v_exp/v_log; |err| ~1e-6, threshold 6.4e-2
__device__ __forceinline__ float softplus_fast(float x) {
    return fmaxf(x, 0.f) + __logf(1.f + __expf(-fabsf(x)));
}

__global__ __launch_bounds__(BDIM)
void yolo_main(const float* __restrict__ pred,
               const float* __restrict__ targets,
               float* __restrict__ partial_sp,   // [GBLK]
               float* __restrict__ partial_tgt) { // [TBLK*4] {cls,loc,obj,spt}
    __shared__ float smem[NTGT * 5 + 16];        // union: target cache / reduce pad
    int lane = threadIdx.x & 63, wid = threadIdx.x >> 6;

    if (blockIdx.x < GBLK) {
        // ---- no-obj gather: one cell per thread, channel 4 only ----
        int tid = blockIdx.x * BDIM + threadIdx.x;
        float sp = softplus_fast(pred[(size_t)tid * Csz + 4]);
        #pragma unroll
        for (int o = 32; o > 0; o >>= 1) sp += __shfl_down(sp, o, 64);
        if (lane == 0) smem[wid] = sp;
        __syncthreads();
        if (threadIdx.x == 0)
            partial_sp[blockIdx.x] = smem[0] + smem[1] + smem[2] + smem[3];
        return;
    }

    // ---- target path: block handles one (b,a); wave handles 16 targets ----
    int ba = blockIdx.x - GBLK;
    for (int i = threadIdx.x; i < NTGT * 5; i += BDIM) smem[i] = targets[i];
    __syncthreads();

    const float* __restrict__ pb = pred + (size_t)ba * HWsz * Csz;
    float cls = 0.f, locv = 0.f, obj = 0.f, spt = 0.f;

    #pragma unroll 4
    for (int k = 0; k < NTGT / 4; ++k) {
        int t = wid * (NTGT / 4) + k;
        const float* tg = &smem[t * 5];
        float cid_f = tg[0];
        int gx = min(max((int)floorf(tg[1] * (float)Wsz), 0), Wsz - 1);
        int gy = min(max((int)floorf(tg[2] * (float)Hsz), 0), Hsz - 1);
        int cell = gy * Wsz + gx;
        const float* p = pb + (size_t)cell * Csz;
        int cid4 = 4 + (int)cid_f;

        float v0 = p[lane];                    // channels 0..63 across lanes
        if (lane < 4) {
            float d = v0 - tg[1 + lane];       // box = targets[:,1:5]
            locv += d * d;
        } else {
            cls += softplus_fast(v0);          // channels 4..63
        }
        if (lane == 4) {                       // channel 4 = objectness
            obj += softplus_fast(-v0);
            spt += softplus_fast(v0);
        }
        if (lane == cid4) cls -= v0;           // onehot subtract (cid<=59)
        if (lane < 20) {
            float v1 = p[64 + lane];           // channels 64..83
            cls += softplus_fast(v1);
            if (lane + 64 == cid4) cls -= v1;  // onehot subtract (cid>=60)
        }
    }

    float vals[4] = {cls, locv, obj, spt};
    #pragma unroll
    for (int q = 0; q < 4; ++q) {
        float v = vals[q];
        #pragma unroll
        for (int o = 32; o > 0; o >>= 1) v += __shfl_down(v, o, 64);
        vals[q] = v;
    }
    __syncthreads();                           // smem reuse (targets -> reduce)
    if (lane == 0) {
        #pragma unroll
        for (int q = 0; q < 4; ++q) smem[wid * 4 + q] = vals[q];
    }
    __syncthreads();
    if (threadIdx.x == 0) {
        #pragma unroll
        for (int q = 0; q < 4; ++q)
            partial_tgt[ba * 4 + q] = smem[q] + smem[4 + q] + smem[8 + q] + smem[12 + q];
    }
}

__global__ __launch_bounds__(BDIM)
void yolo_final(const float* __restrict__ partial_sp,
                const float* __restrict__ partial_tgt,
                float* __restrict__ out) {
    int lane = threadIdx.x & 63, wid = threadIdx.x >> 6;
    float s[5] = {0.f, 0.f, 0.f, 0.f, 0.f};    // {sp_all, cls, loc, obj, spt}
    for (int i = threadIdx.x; i < GBLK; i += BDIM) s[0] += partial_sp[i];
    if (threadIdx.x < TBLK) {
        s[1] = partial_tgt[threadIdx.x * 4 + 0];
        s[2] = partial_tgt[threadIdx.x * 4 + 1];
        s[3] = partial_tgt[threadIdx.x * 4 + 2];
        s[4] = partial_tgt[threadIdx.x * 4 + 3];
    }
    #pragma unroll
    for (int q = 0; q < 5; ++q) {
        float v = s[q];
        #pragma unroll
        for (int o = 32; o > 0; o >>= 1) v += __shfl_down(v, o, 64);
        s[q] = v;
    }
    __shared__ float sm[4][5];
    if (lane == 0) {
        #pragma unroll
        for (int q = 0; q < 5; ++q) sm[wid][q] = s[q];
    }
    __syncthreads();
    if (threadIdx.x == 0) {
        float sp_all = sm[0][0] + sm[1][0] + sm[2][0] + sm[3][0];
        float cls    = sm[0][1] + sm[1][1] + sm[2][1] + sm[3][1];
        float loc    = sm[0][2] + sm[1][2] + sm[2][2] + sm[3][2];
        float obj    = sm[0][3] + sm[1][3] + sm[2][3] + sm[3][3];
        float spt    = sm[0][4] + sm[1][4] + sm[2][4] + sm[3][4];
        float loc_loss = loc / (float)(NCOMBO * 4);                      // 12288
        float cls_loss = cls / (float)(NCOMBO * 80);                     // 245760
        float obj_loss = obj / (float)NCOMBO;                            // 3072
        float noobj    = (sp_all - spt) / (float)(BAsz * (HWsz - NTGT)); // 304128
        out[0] = loc_loss + cls_loss + obj_loss + 0.5f * noobj;
    }
}

extern "C" void kernel_launch(void* const* d_in, const int* in_sizes, int n_in,
                              void* d_out, int out_size, void* d_ws, size_t ws_size,
                              hipStream_t stream) {
    const float* pred    = (const float*)d_in[0];
    const float* targets = (const float*)d_in[1];
    float* partial_sp  = (float*)d_ws;               // 1200 floats, fully rewritten
    float* partial_tgt = partial_sp + GBLK;          // 192 floats, fully rewritten
    float* out = (float*)d_out;

    yolo_main<<<NBLK, BDIM, 0, stream>>>(pred, targets, partial_sp, partial_tgt);
    yolo_final<<<1, BDIM, 0, stream>>>(partial_sp, partial_tgt, out);
}

// Round 5
// 151.646 us; speedup vs baseline: 1.8512x; 1.0261x over previous
//
#include <hip/hip_runtime.h>
#include <math.h>

constexpr int BDIM  = 256;
constexpr int Bsz   = 16, Asz = 3, Hsz = 80, Wsz = 80;
constexpr int Csz   = 84;                 // 4 + 80
constexpr int HWsz  = Hsz * Wsz;          // 6400
constexpr int BAsz  = Bsz * Asz;          // 48
constexpr int TOTAL = BAsz * HWsz;        // 307200
constexpr int NTGT  = 64;
constexpr int NCOMBO = BAsz * NTGT;       // 3072
constexpr int GITER = 8;                  // ch4 loads per thread (MLP)
constexpr int GBLK  = TOTAL / (BDIM * GITER);  // 150 gather blocks
constexpr int TBLK  = BAsz;               // 48 target blocks (one per (b,a))
constexpr int NBLK  = GBLK + TBLK;        // 198
constexpr int NSP   = GBLK * 4;           // per-wave partials: 600
static_assert(GBLK * BDIM * GITER == TOTAL, "exact cover");

// fast softplus: logaddexp(x,0) via hw v_exp/v_log; |err| ~1e-6, threshold 6.4e-2
__device__ __forceinline__ float softplus_fast(float x) {
    return fmaxf(x, 0.f) + __logf(1.f + __expf(-fabsf(x)));
}

__global__ __launch_bounds__(BDIM)
void yolo_main(const float* __restrict__ pred,
               const float* __restrict__ targets,
               float* __restrict__ partial_sp,   // [NSP] per-wave
               float* __restrict__ partial_tgt) { // [TBLK*4] {cls,loc,obj,spt}
    int lane = threadIdx.x & 63, wid = threadIdx.x >> 6;

    if (blockIdx.x < GBLK) {
        // ---- no-obj gather: 8 cells per thread, channel 4 only ----
        // Issue all 8 scattered line loads back-to-back (8 outstanding
        // misses/thread), then softplus+reduce. No LDS, no syncthreads.
        int base = blockIdx.x * (BDIM * GITER) + threadIdx.x;
        float v[GITER];
        #pragma unroll
        for (int k = 0; k < GITER; ++k) {
            v[k] = pred[(size_t)(base + k * BDIM) * Csz + 4];
        }
        float sp = 0.f;
        #pragma unroll
        for (int k = 0; k < GITER; ++k) sp += softplus_fast(v[k]);
        #pragma unroll
        for (int o = 32; o > 0; o >>= 1) sp += __shfl_down(sp, o, 64);
        if (lane == 0) partial_sp[blockIdx.x * 4 + wid] = sp;
        return;
    }

    // ---- target path: block handles one (b,a); wave handles 16 targets ----
    __shared__ float smem[NTGT * 5];
    int ba = blockIdx.x - GBLK;
    for (int i = threadIdx.x; i < NTGT * 5; i += BDIM) smem[i] = targets[i];
    __syncthreads();

    const float* __restrict__ pb = pred + (size_t)ba * HWsz * Csz;
    float cls = 0.f, locv = 0.f, obj = 0.f, spt = 0.f;

    #pragma unroll 4
    for (int k = 0; k < NTGT / 4; ++k) {
        int t = wid * (NTGT / 4) + k;
        const float* tg = &smem[t * 5];
        float cid_f = tg[0];
        int gx = min(max((int)floorf(tg[1] * (float)Wsz), 0), Wsz - 1);
        int gy = min(max((int)floorf(tg[2] * (float)Hsz), 0), Hsz - 1);
        int cell = gy * Wsz + gx;
        const float* p = pb + (size_t)cell * Csz;
        int cid4 = 4 + (int)cid_f;

        float v0 = p[lane];                    // channels 0..63 across lanes
        if (lane < 4) {
            float d = v0 - tg[1 + lane];       // box = targets[:,1:5]
            locv += d * d;
        } else {
            cls += softplus_fast(v0);          // channels 4..63
        }
        if (lane == 4) {                       // channel 4 = objectness
            obj += softplus_fast(-v0);
            spt += softplus_fast(v0);
        }
        if (lane == cid4) cls -= v0;           // onehot subtract (cid<=59)
        if (lane < 20) {
            float v1 = p[64 + lane];           // channels 64..83
            cls += softplus_fast(v1);
            if (lane + 64 == cid4) cls -= v1;  // onehot subtract (cid>=60)
        }
    }

    float vals[4] = {cls, locv, obj, spt};
    #pragma unroll
    for (int q = 0; q < 4; ++q) {
        float v = vals[q];
        #pragma unroll
        for (int o = 32; o > 0; o >>= 1) v += __shfl_down(v, o, 64);
        vals[q] = v;
    }
    __shared__ float rsm[4][4];
    if (lane == 0) {
        #pragma unroll
        for (int q = 0; q < 4; ++q) rsm[wid][q] = vals[q];
    }
    __syncthreads();
    if (threadIdx.x == 0) {
        #pragma unroll
        for (int q = 0; q < 4; ++q)
            partial_tgt[ba * 4 + q] = rsm[0][q] + rsm[1][q] + rsm[2][q] + rsm[3][q];
    }
}

__global__ __launch_bounds__(BDIM)
void yolo_final(const float* __restrict__ partial_sp,
                const float* __restrict__ partial_tgt,
                float* __restrict__ out) {
    int lane = threadIdx.x & 63, wid = threadIdx.x >> 6;
    float s[5] = {0.f, 0.f, 0.f, 0.f, 0.f};    // {sp_all, cls, loc, obj, spt}
    for (int i = threadIdx.x; i < NSP; i += BDIM) s[0] += partial_sp[i];
    if (threadIdx.x < TBLK) {
        s[1] = partial_tgt[threadIdx.x * 4 + 0];
        s[2] = partial_tgt[threadIdx.x * 4 + 1];
        s[3] = partial_tgt[threadIdx.x * 4 + 2];
        s[4] = partial_tgt[threadIdx.x * 4 + 3];
    }
    #pragma unroll
    for (int q = 0; q < 5; ++q) {
        float v = s[q];
        #pragma unroll
        for (int o = 32; o > 0; o >>= 1) v += __shfl_down(v, o, 64);
        s[q] = v;
    }
    __shared__ float sm[4][5];
    if (lane == 0) {
        #pragma unroll
        for (int q = 0; q < 5; ++q) sm[wid][q] = s[q];
    }
    __syncthreads();
    if (threadIdx.x == 0) {
        float sp_all = sm[0][0] + sm[1][0] + sm[2][0] + sm[3][0];
        float cls    = sm[0][1] + sm[1][1] + sm[2][1] + sm[3][1];
        float loc    = sm[0][2] + sm[1][2] + sm[2][2] + sm[3][2];
        float obj    = sm[0][3] + sm[1][3] + sm[2][3] + sm[3][3];
        float spt    = sm[0][4] + sm[1][4] + sm[2][4] + sm[3][4];
        float loc_loss = loc / (float)(NCOMBO * 4);                      // 12288
        float cls_loss = cls / (float)(NCOMBO * 80);                     // 245760
        float obj_loss = obj / (float)NCOMBO;                            // 3072
        float noobj    = (sp_all - spt) / (float)(BAsz * (HWsz - NTGT)); // 304128
        out[0] = loc_loss + cls_loss + obj_loss + 0.5f * noobj;
    }
}

extern "C" void kernel_launch(void* const* d_in, const int* in_sizes, int n_in,
                              void* d_out, int out_size, void* d_ws, size_t ws_size,
                              hipStream_t stream) {
    const float* pred    = (const float*)d_in[0];
    const float* targets = (const float*)d_in[1];
    float* partial_sp  = (float*)d_ws;               // 600 floats, fully rewritten
    float* partial_tgt = partial_sp + NSP;           // 192 floats, fully rewritten
    float* out = (float*)d_out;

    yolo_main<<<NBLK, BDIM, 0, stream>>>(pred, targets, partial_sp, partial_tgt);
    yolo_final<<<1, BDIM, 0, stream>>>(partial_sp, partial_tgt, out);
}